// Round 5
// baseline (393.936 us; speedup 1.0000x reference)
//
#include <hip/hip_runtime.h>
#include <stdint.h>

typedef unsigned short u16;
typedef float f32x4 __attribute__((ext_vector_type(4)));
typedef short s16x8 __attribute__((ext_vector_type(8)));

#define SEQ 2048
#define DM 1024
#define NH 16
#define HD 64
#define BATCH 4
#define ROWS (BATCH*SEQ)   // 8192

__device__ __forceinline__ u16 f32_bf16(float f) {
  union { float f; uint32_t u; } c; c.f = f;
  uint32_t u = c.u;
  return (u16)((u + 0x7fffu + ((u >> 16) & 1u)) >> 16);  // RNE
}
// truncating cast (for P >= 0: bias cancels in softmax normalization)
__device__ __forceinline__ u16 f32_bf16_trunc(float f) {
  union { float f; uint32_t u; } c; c.f = f;
  return (u16)(c.u >> 16);
}

// async global->LDS, 16B per lane. LDS dest = wave-uniform base + lane*16 (NO padding).
#define GLOAD_LDS16(g, l) __builtin_amdgcn_global_load_lds( \
    (__attribute__((address_space(1))) void*)(g),           \
    (__attribute__((address_space(3))) void*)(l), 16, 0, 0)

// ---------------- cast kernels ----------------
__global__ __launch_bounds__(256) void cast_bf16_k(const float* __restrict__ in,
                                                   u16* __restrict__ out, int n4) {
  int i = blockIdx.x * 256 + threadIdx.x;
  if (i >= n4) return;
  float4 v = ((const float4*)in)[i];
  ushort4 o;
  o.x = f32_bf16(v.x); o.y = f32_bf16(v.y); o.z = f32_bf16(v.z); o.w = f32_bf16(v.w);
  ((ushort4*)out)[i] = o;
}

// in [R][C] fp32  ->  out [C][R] bf16
__global__ __launch_bounds__(256) void cast_transpose_k(const float* __restrict__ in,
                                                        u16* __restrict__ out, int R, int C) {
  __shared__ float tile[32][33];
  int c0 = blockIdx.x * 32, r0 = blockIdx.y * 32;
  int t = threadIdx.x;
  int lr = t >> 3, lc = (t & 7) * 4;
  float4 v = *(const float4*)(in + (size_t)(r0 + lr) * C + c0 + lc);
  tile[lr][lc] = v.x; tile[lr][lc + 1] = v.y; tile[lr][lc + 2] = v.z; tile[lr][lc + 3] = v.w;
  __syncthreads();
  ushort4 o;
  o.x = f32_bf16(tile[lc + 0][lr]);
  o.y = f32_bf16(tile[lc + 1][lr]);
  o.z = f32_bf16(tile[lc + 2][lr]);
  o.w = f32_bf16(tile[lc + 3][lr]);
  *(ushort4*)(out + (size_t)(c0 + lr) * R + r0 + lc) = o;
}

#define QSCALE 0.18033688011112042f   // (1/sqrt(64)) * log2(e)

// ---------------- QKV GEMM: 256x384 tile, BK=32, ring-3 LDS, overlapped pipeline ------
// Grid 8x32 = 256 blocks = EXACTLY 1/CU, single dispatch round (no tail; the previous
// 384-block grid lost 25% to a half-empty second round). 512 threads = 8 waves (2Mx4N),
// per-wave 128x96 output, acc[8][6] (192 acc regs), 48 MFMA per wave per K-tile.
// LDS ring-3: per buf A 256x32 (16KB) + B 384x32 (24KB) -> 120 KiB.
// Per tile, 2 barriers; fragment reads for the NEXT cluster issued BEFORE the current
// cluster, completed by counted lgkmcnt (4 / 10, never 0 mid-loop); staging of tile T+2
// issued during tile T, completed by vmcnt(5) at tile end (T+1's 5 loads drained, T+2's
// 5 stay in flight).
// WAR safety (ring-3): stage target buf (T+2)%3 == (T-1)%3; all reads of it completed
// before that tile's own lgkm-counted waits, which precede bar1(T-1) < bar2(T) < writes.
// LDS XOR swizzle (16B granules, slot ^= (row>>1)&3) on pre-swizzled GLOBAL source +
// swizzled ds_read address (same involution); linear global_load_lds dest. Bank-optimal
// (measured 0 conflicts).

__device__ __forceinline__ f32x4 mfma16(s16x8 a, s16x8 b, f32x4 c) {
  return __builtin_amdgcn_mfma_f32_16x16x32_bf16(a, b, c, 0, 0, 0);
}

template<int STG, int ENDVM, int LAST>
__device__ __forceinline__ void tile_step(
    const u16* lAc, const u16* lBc,   // buf T (current)
    const u16* lAn, const u16* lBn,   // buf T+1 (next; frag prefetch source)
    u16* lAs, u16* lBs,               // buf T+2 (stage dest)
    const u16* gA0, const u16* gA1,
    const u16* gB0, const u16* gB1, const u16* gB2,
    int d0, int d1, int e2, int aoff, int boff,
    s16x8 (&fa)[4], s16x8 (&fb)[6],   // tile T phase-0 frags (preloaded last tile)
    s16x8 (&na)[4], s16x8 (&nb)[6],   // tile T+1 frag storage (ping-pong)
    f32x4 (&acc)[8][6])
{
  __builtin_amdgcn_s_barrier();                       // bar2 (WAR fence for stage)
  __builtin_amdgcn_sched_barrier(0);
  s16x8 f1[4];                                        // A-high frags of tile T
#pragma unroll
  for (int mi = 0; mi < 4; ++mi) f1[mi] = *(const s16x8*)&lAc[aoff + 2048 + mi * 512];
  if (STG) { GLOAD_LDS16(gA0, lAs + d0); GLOAD_LDS16(gA1, lAs + d1); }
  asm volatile("s_waitcnt lgkmcnt(4)" ::: "memory");  // fa/fb resident; f1 in flight
  __builtin_amdgcn_sched_barrier(0);
  __builtin_amdgcn_s_setprio(1);
#pragma unroll
  for (int mi = 0; mi < 4; ++mi)
#pragma unroll
    for (int ni = 0; ni < 6; ++ni)
      acc[mi][ni] = mfma16(fa[mi], fb[ni], acc[mi][ni]);
  __builtin_amdgcn_s_setprio(0);
  __builtin_amdgcn_sched_barrier(0);
  if (STG) { GLOAD_LDS16(gB0, lBs + d0); GLOAD_LDS16(gB1, lBs + d1); GLOAD_LDS16(gB2, lBs + e2); }
  if (ENDVM == 5)      asm volatile("s_waitcnt vmcnt(5)" ::: "memory");
  else if (ENDVM == 0) asm volatile("s_waitcnt vmcnt(0)" ::: "memory");
  __builtin_amdgcn_s_barrier();                       // bar1: buf T+1 ready for reads
  __builtin_amdgcn_sched_barrier(0);
  if (!LAST) {
#pragma unroll
    for (int ni = 0; ni < 6; ++ni) nb[ni] = *(const s16x8*)&lBn[boff + ni * 512];
#pragma unroll
    for (int mi = 0; mi < 4; ++mi) na[mi] = *(const s16x8*)&lAn[aoff + mi * 512];
    asm volatile("s_waitcnt lgkmcnt(10)" ::: "memory"); // f1 resident; na/nb in flight
  } else {
    asm volatile("s_waitcnt lgkmcnt(0)" ::: "memory");
  }
  __builtin_amdgcn_sched_barrier(0);
  __builtin_amdgcn_s_setprio(1);
#pragma unroll
  for (int mi = 0; mi < 4; ++mi)
#pragma unroll
    for (int ni = 0; ni < 6; ++ni)
      acc[4 + mi][ni] = mfma16(f1[mi], fb[ni], acc[4 + mi][ni]);
  __builtin_amdgcn_s_setprio(0);
  __builtin_amdgcn_sched_barrier(0);
}

__global__ __launch_bounds__(512, 2) void qkv_gemm(
    const u16* __restrict__ A, const u16* __restrict__ Bt,
    u16* __restrict__ Qo, u16* __restrict__ Ko, u16* __restrict__ Vo)
{
  __shared__ u16 lA[3][8192];    // 3 ring bufs x [256 rows][32 k] bf16 (16 KB each)
  __shared__ u16 lB[3][12288];   // 3 ring bufs x [384 rows][32 k] bf16 (24 KB each)
  int t = threadIdx.x;

  // XCD-aware bijective swizzle (256 = 8 * 32): XCD k gets a 4x8 (m x n) tile patch
  int flat = blockIdx.y * 8 + blockIdx.x;    // grid (8, 32)
  int swz = (flat & 7) * 32 + (flat >> 3);
  int by = swz >> 3, bx = swz & 7;
  int m0 = by * 256, n0 = bx * 384;

  int lane = t & 63, w = t >> 6;
  int m16 = lane & 15, quad = lane >> 4;
  int wm = w >> 2, wn = w & 3;               // 2 x 4 wave grid

  // staging: A 1024 chunks (2/thread), B 1536 chunks (3/thread); chunk c: row=c>>2,
  // slot j=c&3; source slot = j ^ ((c>>3)&3) = j ^ ((row>>1)&3) (involution).
  int r0 = t >> 2;
  int scol = ((t & 3) ^ ((t >> 3) & 3)) * 8; // pre-swizzled source column (elements)
  const u16* Ag0 = A  + (size_t)(m0 + r0) * DM + scol;
  const u16* Ag1 = A  + (size_t)(m0 + 128 + r0) * DM + scol;
  const u16* Bg0 = Bt + (size_t)(n0 + r0) * DM + scol;
  const u16* Bg1 = Bt + (size_t)(n0 + 128 + r0) * DM + scol;
  const u16* Bg2 = Bt + (size_t)(n0 + 256 + r0) * DM + scol;
  int d0 = t * 8, d1 = 4096 + t * 8, e2 = 8192 + t * 8;   // linear LDS dests (elements)

  // fragment reads: row*32 + (quad ^ ((row>>1)&3))*8 ; all row bases are mult of 16
  int ka = (quad ^ ((m16 >> 1) & 3)) * 8;
  int aoff = (wm * 128 + m16) * 32 + ka;
  int boff = (wn * 96 + m16) * 32 + ka;

  f32x4 acc[8][6];
#pragma unroll
  for (int mi = 0; mi < 8; ++mi)
#pragma unroll
    for (int ni = 0; ni < 6; ++ni)
#pragma unroll
      for (int r = 0; r < 4; ++r) acc[mi][ni][r] = 0.f;

  // prologue: stage tiles 0,1 (10 loads/thread), wait tile 0 (tile 1's 5 in flight)
#pragma unroll
  for (int kt = 0; kt < 2; ++kt) {
    GLOAD_LDS16(Ag0 + kt * 32, lA[kt] + d0);
    GLOAD_LDS16(Ag1 + kt * 32, lA[kt] + d1);
    GLOAD_LDS16(Bg0 + kt * 32, lB[kt] + d0);
    GLOAD_LDS16(Bg1 + kt * 32, lB[kt] + d1);
    GLOAD_LDS16(Bg2 + kt * 32, lB[kt] + e2);
  }
  asm volatile("s_waitcnt vmcnt(5)" ::: "memory");
  __builtin_amdgcn_s_barrier();
  __builtin_amdgcn_sched_barrier(0);

  // initial phase-0 fragments of tile 0 (ping-pong set 0)
  s16x8 fa0[4], fa1[4];
  s16x8 fb0[6], fb1[6];
#pragma unroll
  for (int ni = 0; ni < 6; ++ni) fb0[ni] = *(const s16x8*)&lB[0][boff + ni * 512];
#pragma unroll
  for (int mi = 0; mi < 4; ++mi) fa0[mi] = *(const s16x8*)&lA[0][aoff + mi * 512];

  // main loop: tiles 0..29 in groups of 6 (lcm of ring-3 and reg ping-pong)
  for (int it = 0; it < 5; ++it) {
    int T = 6 * it;
    tile_step<1, 5, 0>(lA[0], lB[0], lA[1], lB[1], lA[2], lB[2],
                       Ag0 + (T + 2) * 32, Ag1 + (T + 2) * 32,
                       Bg0 + (T + 2) * 32, Bg1 + (T + 2) * 32, Bg2 + (T + 2) * 32,
                       d0, d1, e2, aoff, boff, fa0, fb0, fa1, fb1, acc);
    tile_step<1, 5, 0>(lA[1], lB[1], lA[2], lB[2], lA[0], lB[0],
                       Ag0 + (T + 3) * 32, Ag1 + (T + 3) * 32,
                       Bg0 + (T + 3) * 32, Bg1 + (T + 3) * 32, Bg2 + (T + 3) * 32,
                       d0, d1, e2, aoff, boff, fa1, fb1, fa0, fb0, acc);
    tile_step<1, 5, 0>(lA[2], lB[2], lA[0], lB[0], lA[1], lB[1],
                       Ag0 + (T + 4) * 32, Ag1 + (T + 4) * 32,
                       Bg0 + (T + 4) * 32, Bg1 + (T + 4) * 32, Bg2 + (T + 4) * 32,
                       d0, d1, e2, aoff, boff, fa0, fb0, fa1, fb1, acc);
    tile_step<1, 5, 0>(lA[0], lB[0], lA[1], lB[1], lA[2], lB[2],
                       Ag0 + (T + 5) * 32, Ag1 + (T + 5) * 32,
                       Bg0 + (T + 5) * 32, Bg1 + (T + 5) * 32, Bg2 + (T + 5) * 32,
                       d0, d1, e2, aoff, boff, fa1, fb1, fa0, fb0, acc);
    tile_step<1, 5, 0>(lA[1], lB[1], lA[2], lB[2], lA[0], lB[0],
                       Ag0 + (T + 6) * 32, Ag1 + (T + 6) * 32,
                       Bg0 + (T + 6) * 32, Bg1 + (T + 6) * 32, Bg2 + (T + 6) * 32,
                       d0, d1, e2, aoff, boff, fa0, fb0, fa1, fb1, acc);
    tile_step<1, 5, 0>(lA[2], lB[2], lA[0], lB[0], lA[1], lB[1],
                       Ag0 + (T + 7) * 32, Ag1 + (T + 7) * 32,
                       Bg0 + (T + 7) * 32, Bg1 + (T + 7) * 32, Bg2 + (T + 7) * 32,
                       d0, d1, e2, aoff, boff, fa1, fb1, fa0, fb0, acc);
  }
  // tiles 30 (wait remaining tile-31 loads) and 31 (drain)
  tile_step<0, 0, 0>(lA[0], lB[0], lA[1], lB[1], lA[2], lB[2],
                     Ag0, Ag1, Bg0, Bg1, Bg2,
                     d0, d1, e2, aoff, boff, fa0, fb0, fa1, fb1, acc);
  tile_step<0, -1, 1>(lA[1], lB[1], lA[2], lB[2], lA[0], lB[0],
                      Ag0, Ag1, Bg0, Bg1, Bg2,
                      d0, d1, e2, aoff, boff, fa1, fb1, fa0, fb0, acc);

  // epilogue: split Q (scaled) / K / V (transposed). sec/h/d computed per 16-col
  // group; 16-col spans never straddle the 1024-boundaries (all offsets mult of 16).
#pragma unroll
  for (int mi = 0; mi < 8; ++mi) {
    int gr = m0 + wm * 128 + mi * 16 + quad * 4;   // multiple of 4, no batch crossing
    int b = gr >> 11, tt = gr & 2047;
#pragma unroll
    for (int ni = 0; ni < 6; ++ni) {
      int gc = n0 + wn * 96 + ni * 16 + m16;
      int sec = gc >> 10, rem = gc & 1023, h = rem >> 6, d = rem & 63;
      if (sec == 0) {
#pragma unroll
        for (int r = 0; r < 4; ++r)
          Qo[(((size_t)b * NH + h) * SEQ + tt + r) * HD + d] = f32_bf16(acc[mi][ni][r] * QSCALE);
      } else if (sec == 1) {
#pragma unroll
        for (int r = 0; r < 4; ++r)
          Ko[(((size_t)b * NH + h) * SEQ + tt + r) * HD + d] = f32_bf16(acc[mi][ni][r]);
      } else {
        ushort4 o;
        o.x = f32_bf16(acc[mi][ni][0]); o.y = f32_bf16(acc[mi][ni][1]);
        o.z = f32_bf16(acc[mi][ni][2]); o.w = f32_bf16(acc[mi][ni][3]);
        *(ushort4*)&Vo[(((size_t)b * NH + h) * HD + d) * SEQ + tt] = o;  // V^T [b][h][d][t]
      }
    }
  }
}

// ---------------- GEMM (out-proj): C[M,N] = A[M,K] * Bt[N,K]^T, bf16 in, fp32 out ----
template<int EPI>
__global__ __launch_bounds__(256) void gemm_bt(
    const u16* __restrict__ A, const u16* __restrict__ Bt,
    float* __restrict__ Cf, u16* __restrict__ Qo, u16* __restrict__ Ko, u16* __restrict__ Vo,
    int M, int N, int K)
{
  __shared__ u16 As[128 * 32];
  __shared__ u16 Bs[128 * 32];
  int t = threadIdx.x;
  int m0 = blockIdx.y * 128, n0 = blockIdx.x * 128;

  int srow = t >> 2, scol8 = (t & 3) * 8;
  const u16* Ag0 = A  + (size_t)(m0 + srow) * K + scol8;
  const u16* Ag1 = A  + (size_t)(m0 + 64 + srow) * K + scol8;
  const u16* Bg0 = Bt + (size_t)(n0 + srow) * K + scol8;
  const u16* Bg1 = Bt + (size_t)(n0 + 64 + srow) * K + scol8;
  u16* Al0 = As + t * 8;  u16* Al1 = As + 2048 + t * 8;
  u16* Bl0 = Bs + t * 8;  u16* Bl1 = Bs + 2048 + t * 8;

  int lane = t & 63, w = t >> 6;
  int m16 = lane & 15, quad = lane >> 4;
  int wr = (w >> 1) * 64, wc = (w & 1) * 64;

  f32x4 acc[4][4];
#pragma unroll
  for (int mi = 0; mi < 4; ++mi)
#pragma unroll
    for (int ni = 0; ni < 4; ++ni)
#pragma unroll
      for (int r = 0; r < 4; ++r) acc[mi][ni][r] = 0.f;

  for (int k0 = 0; k0 < K; k0 += 32) {
    __syncthreads();
    GLOAD_LDS16(Ag0 + k0, Al0);
    GLOAD_LDS16(Ag1 + k0, Al1);
    GLOAD_LDS16(Bg0 + k0, Bl0);
    GLOAD_LDS16(Bg1 + k0, Bl1);
    __syncthreads();
    s16x8 af[4], bf[4];
#pragma unroll
    for (int mi = 0; mi < 4; ++mi)
      af[mi] = *(const s16x8*)(As + (wr + mi * 16 + m16) * 32 + quad * 8);
#pragma unroll
    for (int ni = 0; ni < 4; ++ni)
      bf[ni] = *(const s16x8*)(Bs + (wc + ni * 16 + m16) * 32 + quad * 8);
#pragma unroll
    for (int mi = 0; mi < 4; ++mi)
#pragma unroll
      for (int ni = 0; ni < 4; ++ni)
        acc[mi][ni] = __builtin_amdgcn_mfma_f32_16x16x32_bf16(af[mi], bf[ni], acc[mi][ni], 0, 0, 0);
  }

  if (EPI == 0) {
#pragma unroll
    for (int mi = 0; mi < 4; ++mi) {
      int gr = m0 + wr + mi * 16 + quad * 4;
#pragma unroll
      for (int ni = 0; ni < 4; ++ni) {
        int gc = n0 + wc + ni * 16 + m16;
#pragma unroll
        for (int r = 0; r < 4; ++r)
          Cf[(size_t)(gr + r) * N + gc] = acc[mi][ni][r];
      }
    }
  } else {
#pragma unroll
    for (int mi = 0; mi < 4; ++mi) {
      int gr = m0 + wr + mi * 16 + quad * 4;
      int b = gr >> 11, tt = gr & 2047;
#pragma unroll
      for (int ni = 0; ni < 4; ++ni) {
        int gc = n0 + wc + ni * 16 + m16;
        int sec = gc >> 10, rem = gc & 1023, h = rem >> 6, d = rem & 63;
        if (sec == 0) {
#pragma unroll
          for (int r = 0; r < 4; ++r)
            Qo[(((size_t)b * NH + h) * SEQ + tt + r) * HD + d] = f32_bf16(acc[mi][ni][r] * QSCALE);
        } else if (sec == 1) {
#pragma unroll
          for (int r = 0; r < 4; ++r)
            Ko[(((size_t)b * NH + h) * SEQ + tt + r) * HD + d] = f32_bf16(acc[mi][ni][r]);
        } else {
          ushort4 o;
          o.x = f32_bf16(acc[mi][ni][0]); o.y = f32_bf16(acc[mi][ni][1]);
          o.z = f32_bf16(acc[mi][ni][2]); o.w = f32_bf16(acc[mi][ni][3]);
          *(ushort4*)&Vo[(((size_t)b * NH + h) * HD + d) * SEQ + tt] = o;
        }
      }
    }
  }
}

// ---------------- flash attention, causal, QBLK=128, swapped-QK^T, NO-MAX softmax ------
// grid (8, 64); block 256 = 4 waves, each wave owns 32 q-rows (two 16-row frag sets).
// Block xb does q-tiles {xb, 15-xb} of 128 rows: 34 k-tile units per block, uniform.
// XCD grouping: 8 blocks of one bh land on one XCD (8 bh/XCD -> K+V in L2).
__global__ __launch_bounds__(256) void attn_k(
    const u16* __restrict__ Q, const u16* __restrict__ K,
    const u16* __restrict__ Vt_g,   // [B,H,HD,SEQ]
    u16* __restrict__ O)
{
  __shared__ u16 Ks[64][72];      // [key][d]   (144B rows: 16B-aligned)
  __shared__ u16 Vt[64][72];      // [d][key]
  __shared__ u16 Ps[4][32][72];   // per wave: [qrow 0..31][key]
  int flat = blockIdx.y * 8 + blockIdx.x;    // grid (8, 64) = 512 blocks
  int xcd = flat & 7, pos = flat >> 3;
  int bh = xcd * 8 + (pos >> 3);             // 8 bh per XCD
  int xb = pos & 7;                          // 0..7
  int t = threadIdx.x, w = t >> 6, lane = t & 63;
  int m16 = lane & 15, quad = lane >> 4;
  int b = bh >> 4, h = bh & 15;

  int srow = t >> 2, sc = (t & 3) * 16;
  const u16* Kg0 = K    + ((size_t)bh * SEQ + srow) * HD  + sc;   // key=srow, d=sc..
  const u16* Vg0 = Vt_g + ((size_t)bh * HD  + srow) * SEQ + sc;   // d=srow,  key=sc..

  for (int half = 0; half < 2; ++half) {
    int qt = half ? (15 - xb) : xb;
    int q0 = qt * 128;

    // Q frags: set A rows q0 + w*32 + m16, set B rows +16 (scale pre-folded into Q)
    const u16* QbA = Q + ((size_t)bh * SEQ + q0 + w * 32 + m16) * HD + quad * 8;
    s16x8 qA0 = *(const s16x8*)QbA;
    s16x8 qA1 = *(const s16x8*)(QbA + 32);
    s16x8 qB0 = *(const s16x8*)(QbA + 16 * HD);
    s16x8 qB1 = *(const s16x8*)(QbA + 16 * HD + 32);

    f32x4 accA[4], accB[4];
    float lA = 0.f, lB = 0.f;
#pragma unroll
    for (int ni = 0; ni < 4; ++ni)
#pragma unroll
      for (int r = 0; r < 4; ++r) { accA[ni][r] = 0.f; accB[ni][r] = 0.f; }

    int ktmax = 2 * qt + 1;
    for (int kt = 0; kt <= ktmax; ++kt) {
      uint4 kv0 = *(const uint4*)(Kg0 + (size_t)kt * 64 * HD);
      uint4 kv1 = *(const uint4*)(Kg0 + (size_t)kt * 64 * HD + 8);
      uint4 vv0 = *(const uint4*)(Vg0 + kt * 64);
      uint4 vv1 = *(const uint4*)(Vg0 + kt * 64 + 8);
      __syncthreads();   // previous tile's LDS reads done
      *(uint4*)&Ks[srow][sc]     = kv0;
      *(uint4*)&Ks[srow][sc + 8] = kv1;
      *(uint4*)&Vt[srow][sc]     = vv0;
      *(uint4*)&Vt[srow][sc + 8] = vv1;
      __syncthreads();

      // S^T = K Q^T
      f32x4 sA[4], sB[4];
#pragma unroll
      for (int ni = 0; ni < 4; ++ni)
#pragma unroll
        for (int r = 0; r < 4; ++r) { sA[ni][r] = 0.f; sB[ni][r] = 0.f; }
#pragma unroll
      for (int ni = 0; ni < 4; ++ni) {
        s16x8 kf0 = *(const s16x8*)&Ks[ni * 16 + m16][quad * 8];
        s16x8 kf1 = *(const s16x8*)&Ks[ni * 16 + m16][32 + quad * 8];
        sA[ni] = mfma16(kf0, qA0, sA[ni]);
        sA[ni] = mfma16(kf1, qA1, sA[ni]);
        sB[ni] = mfma16(kf0, qB0, sB[ni]);
        sB[ni] = mfma16(kf1, qB1, sB[ni]);
      }
      if (kt >= 2 * qt) {   // diagonal region: causal mask (exp2(-1e30) -> 0)
        int qga = q0 + w * 32 + m16;
#pragma unroll
        for (int ni = 0; ni < 4; ++ni) {
          int kb = kt * 64 + ni * 16 + quad * 4;
#pragma unroll
          for (int r = 0; r < 4; ++r) {
            if (kb + r > qga)      sA[ni][r] = -1e30f;
            if (kb + r > qga + 16) sB[ni][r] = -1e30f;
          }
        }
      }

      // p = exp2(S); per-lane l partial (q = m16 row); P write as ushort4 (b64)
#pragma unroll
      for (int ni = 0; ni < 4; ++ni) {
        ushort4 oA, oB;
#pragma unroll
        for (int r = 0; r < 4; ++r) {
          float pA = __builtin_amdgcn_exp2f(sA[ni][r]);
          float pB = __builtin_amdgcn_exp2f(sB[ni][r]);
          lA += pA; lB += pB;
          ((u16*)&oA)[r] = f32_bf16_trunc(pA);
          ((u16*)&oB)[r] = f32_bf16_trunc(pB);
        }
        *(ushort4*)&Ps[w][m16][ni * 16 + quad * 4]      = oA;
        *(ushort4*)&Ps[w][16 + m16][ni * 16 + quad * 4] = oB;
      }

      // no barrier: Ps is same-wave write->read, ordered by lgkmcnt
#pragma unroll
      for (int ks = 0; ks < 2; ++ks) {
        s16x8 pA = *(const s16x8*)&Ps[w][m16][ks * 32 + quad * 8];
        s16x8 pB = *(const s16x8*)&Ps[w][16 + m16][ks * 32 + quad * 8];
#pragma unroll
        for (int ni = 0; ni < 4; ++ni) {
          s16x8 vf = *(const s16x8*)&Vt[ni * 16 + m16][ks * 32 + quad * 8];
          accA[ni] = mfma16(pA, vf, accA[ni]);
          accB[ni] = mfma16(pB, vf, accB[ni]);
        }
      }
    }

    // l: reduce over the 4 quad lanes (keys split across quads)
    lA += __shfl_xor(lA, 16, 64);
    lA += __shfl_xor(lA, 32, 64);
    lB += __shfl_xor(lB, 16, 64);
    lB += __shfl_xor(lB, 32, 64);

    // epilogue: O rows q = q0 + w*32 + (quad*4+r) [+16 for set B]; l lives at
    // lanes with m16 == qrow -> redistribute with one shfl per r
#pragma unroll
    for (int r = 0; r < 4; ++r) {
      int src = (lane & 48) | (quad * 4 + r);
      float la = __shfl(lA, src, 64);
      float lb = __shfl(lB, src, 64);
      float ia = 1.f / la, ib = 1.f / lb;
      int qa = q0 + w * 32 + quad * 4 + r;
      size_t baseA = ((size_t)(b * SEQ + qa)) * DM + h * HD;
      size_t baseB = baseA + (size_t)16 * DM;
#pragma unroll
      for (int ni = 0; ni < 4; ++ni) {
        O[baseA + ni * 16 + m16] = f32_bf16(accA[ni][r] * ia);
        O[baseB + ni * 16 + m16] = f32_bf16(accB[ni][r] * ib);
      }
    }
  }
}

// ---------------- launch ----------------
extern "C" void kernel_launch(void* const* d_in, const int* in_sizes, int n_in,
                              void* d_out, int out_size, void* d_ws, size_t ws_size,
                              hipStream_t stream) {
  const float* x    = (const float*)d_in[0];   // [4,2048,1024]
  const float* Wqkv = (const float*)d_in[1];   // [1024,3072]
  const float* Wout = (const float*)d_in[2];   // [1024,1024]
  float* out = (float*)d_out;                  // [4,2048,1024] fp32

  u16* ws = (u16*)d_ws;
  size_t off = 0;
  u16* x_bf   = ws + off; off += (size_t)ROWS * DM;
  u16* wqkv_t = ws + off; off += (size_t)(3 * DM) * DM;
  u16* wout_t = ws + off; off += (size_t)DM * DM;
  u16* Qb     = ws + off; off += (size_t)BATCH * NH * SEQ * HD;
  u16* Kb     = ws + off; off += (size_t)BATCH * NH * SEQ * HD;
  u16* Vb     = ws + off; off += (size_t)BATCH * NH * SEQ * HD;  // [B,H,HD,T]
  u16* AO     = ws + off; off += (size_t)ROWS * DM;

  cast_bf16_k<<<(ROWS * DM / 4 + 255) / 256, 256, 0, stream>>>(x, x_bf, ROWS * DM / 4);
  cast_transpose_k<<<dim3(3 * DM / 32, DM / 32), 256, 0, stream>>>(Wqkv, wqkv_t, DM, 3 * DM);
  cast_transpose_k<<<dim3(DM / 32, DM / 32), 256, 0, stream>>>(Wout, wout_t, DM, DM);
  qkv_gemm<<<dim3(8, 32), 512, 0, stream>>>(x_bf, wqkv_t, Qb, Kb, Vb);
  attn_k<<<dim3(8, BATCH * NH), 256, 0, stream>>>(Qb, Kb, Vb, AO);
  gemm_bt<0><<<dim3(DM / 128, ROWS / 128), 256, 0, stream>>>(
      AO, wout_t, out, nullptr, nullptr, nullptr, ROWS, DM, DM);
}

// Round 6
// 283.969 us; speedup vs baseline: 1.3872x; 1.3872x over previous
//
#include <hip/hip_runtime.h>
#include <stdint.h>

typedef unsigned short u16;
typedef float f32x4 __attribute__((ext_vector_type(4)));
typedef short s16x8 __attribute__((ext_vector_type(8)));

#define SEQ 2048
#define DM 1024
#define NH 16
#define HD 64
#define BATCH 4
#define ROWS (BATCH*SEQ)   // 8192

__device__ __forceinline__ u16 f32_bf16(float f) {
  union { float f; uint32_t u; } c; c.f = f;
  uint32_t u = c.u;
  return (u16)((u + 0x7fffu + ((u >> 16) & 1u)) >> 16);  // RNE
}
// truncating cast (for P >= 0: bias cancels in softmax normalization)
__device__ __forceinline__ u16 f32_bf16_trunc(float f) {
  union { float f; uint32_t u; } c; c.f = f;
  return (u16)(c.u >> 16);
}

// async global->LDS, 16B per lane. LDS dest = wave-uniform base + lane*16 (NO padding).
#define GLOAD_LDS16(g, l) __builtin_amdgcn_global_load_lds( \
    (__attribute__((address_space(1))) void*)(g),           \
    (__attribute__((address_space(3))) void*)(l), 16, 0, 0)

// ---------------- cast kernels ----------------
__global__ __launch_bounds__(256) void cast_bf16_k(const float* __restrict__ in,
                                                   u16* __restrict__ out, int n4) {
  int i = blockIdx.x * 256 + threadIdx.x;
  if (i >= n4) return;
  float4 v = ((const float4*)in)[i];
  ushort4 o;
  o.x = f32_bf16(v.x); o.y = f32_bf16(v.y); o.z = f32_bf16(v.z); o.w = f32_bf16(v.w);
  ((ushort4*)out)[i] = o;
}

// in [R][C] fp32  ->  out [C][R] bf16
__global__ __launch_bounds__(256) void cast_transpose_k(const float* __restrict__ in,
                                                        u16* __restrict__ out, int R, int C) {
  __shared__ float tile[32][33];
  int c0 = blockIdx.x * 32, r0 = blockIdx.y * 32;
  int t = threadIdx.x;
  int lr = t >> 3, lc = (t & 7) * 4;
  float4 v = *(const float4*)(in + (size_t)(r0 + lr) * C + c0 + lc);
  tile[lr][lc] = v.x; tile[lr][lc + 1] = v.y; tile[lr][lc + 2] = v.z; tile[lr][lc + 3] = v.w;
  __syncthreads();
  ushort4 o;
  o.x = f32_bf16(tile[lc + 0][lr]);
  o.y = f32_bf16(tile[lc + 1][lr]);
  o.z = f32_bf16(tile[lc + 2][lr]);
  o.w = f32_bf16(tile[lc + 3][lr]);
  *(ushort4*)(out + (size_t)(c0 + lr) * R + r0 + lc) = o;
}

#define QSCALE 0.18033688011112042f   // (1/sqrt(64)) * log2(e)

// ---------------- QKV GEMM: 256x256 tile, BK=32, ring-4 LDS, overlapped pipeline ------
// (Round-4 version, verbatim: 82.4 us measured, 0 bank conflicts, no spill.
//  acc[8][4]=128 + ping-pong frags 80 + f1 16 ~= 230 VGPR < 256 cap. Do NOT widen the
//  tile: 256x384 needs ~320 VGPR -> spills to scratch (654 MB WRITE_SIZE, R5).)

__device__ __forceinline__ f32x4 mfma16(s16x8 a, s16x8 b, f32x4 c) {
  return __builtin_amdgcn_mfma_f32_16x16x32_bf16(a, b, c, 0, 0, 0);
}

template<int STG, int ENDVM, int LAST>
__device__ __forceinline__ void tile_step(
    const u16* lAc, const u16* lBc,   // buf T (current)
    const u16* lAn, const u16* lBn,   // buf T+1 (next; frag prefetch source)
    u16* lAs, u16* lBs,               // buf T+3 (stage dest)
    const u16* gA0, const u16* gA1, const u16* gB0, const u16* gB1,
    int d0, int d1, int aoff, int boff,
    s16x8 (&fa)[4], s16x8 (&fb)[4],   // tile T phase-0 frags (preloaded last tile)
    s16x8 (&na)[4], s16x8 (&nb)[4],   // tile T+1 frag storage (ping-pong)
    f32x4 (&acc)[8][4])
{
  __builtin_amdgcn_s_barrier();                       // bar2 (WAR fence for stage)
  __builtin_amdgcn_sched_barrier(0);
  s16x8 f1[4];                                        // A-high frags of tile T
#pragma unroll
  for (int mi = 0; mi < 4; ++mi) f1[mi] = *(const s16x8*)&lAc[aoff + 2048 + mi * 512];
  if (STG) { GLOAD_LDS16(gA0, lAs + d0); GLOAD_LDS16(gA1, lAs + d1); }
  asm volatile("s_waitcnt lgkmcnt(4)" ::: "memory");  // fa/fb resident; f1 in flight
  __builtin_amdgcn_sched_barrier(0);
  __builtin_amdgcn_s_setprio(1);
#pragma unroll
  for (int mi = 0; mi < 4; ++mi)
#pragma unroll
    for (int ni = 0; ni < 4; ++ni)
      acc[mi][ni] = mfma16(fa[mi], fb[ni], acc[mi][ni]);
  __builtin_amdgcn_s_setprio(0);
  __builtin_amdgcn_sched_barrier(0);
  if (STG) { GLOAD_LDS16(gB0, lBs + d0); GLOAD_LDS16(gB1, lBs + d1); }
  if (ENDVM == 8)      asm volatile("s_waitcnt vmcnt(8)" ::: "memory");
  else if (ENDVM == 4) asm volatile("s_waitcnt vmcnt(4)" ::: "memory");
  else if (ENDVM == 0) asm volatile("s_waitcnt vmcnt(0)" ::: "memory");
  __builtin_amdgcn_s_barrier();                       // bar1: buf T+1 ready for reads
  __builtin_amdgcn_sched_barrier(0);
  if (!LAST) {
#pragma unroll
    for (int ni = 0; ni < 4; ++ni) nb[ni] = *(const s16x8*)&lBn[boff + ni * 512];
#pragma unroll
    for (int mi = 0; mi < 4; ++mi) na[mi] = *(const s16x8*)&lAn[aoff + mi * 512];
    asm volatile("s_waitcnt lgkmcnt(8)" ::: "memory"); // f1 resident; na/nb in flight
  } else {
    asm volatile("s_waitcnt lgkmcnt(0)" ::: "memory");
  }
  __builtin_amdgcn_sched_barrier(0);
  __builtin_amdgcn_s_setprio(1);
#pragma unroll
  for (int mi = 0; mi < 4; ++mi)
#pragma unroll
    for (int ni = 0; ni < 4; ++ni)
      acc[4 + mi][ni] = mfma16(f1[mi], fb[ni], acc[4 + mi][ni]);
  __builtin_amdgcn_s_setprio(0);
  __builtin_amdgcn_sched_barrier(0);
}

__global__ __launch_bounds__(512, 2) void qkv_gemm(
    const u16* __restrict__ A, const u16* __restrict__ Bt,
    u16* __restrict__ Qo, u16* __restrict__ Ko, u16* __restrict__ Vo)
{
  __shared__ u16 lA[4][8192];   // 4 ring bufs x [256 rows][32 k] bf16
  __shared__ u16 lB[4][8192];
  int t = threadIdx.x;

  // XCD-aware bijective swizzle of the flat block id (384 = 8 * 48)
  int flat = blockIdx.y * 12 + blockIdx.x;   // grid (12, 32)
  int swz = (flat & 7) * 48 + (flat >> 3);
  int by = swz / 12, bx = swz - by * 12;
  int m0 = by * 256, n0 = bx * 256;

  int lane = t & 63, w = t >> 6;
  int m16 = lane & 15, quad = lane >> 4;
  int wm = w >> 2, wn = w & 3;               // 2 x 4 wave grid

  // staging: 1024 16B-chunks per 16KB operand tile; thread t covers chunks t, 512+t.
  // chunk c: row = c>>2, in-row slot j = c&3; source slot = j ^ ((c>>3)&3) (involution).
  int r0 = t >> 2;
  int scol = ((t & 3) ^ ((t >> 3) & 3)) * 8; // pre-swizzled source column (elements)
  const u16* Ag0 = A  + (size_t)(m0 + r0) * DM + scol;
  const u16* Ag1 = A  + (size_t)(m0 + 128 + r0) * DM + scol;
  const u16* Bg0 = Bt + (size_t)(n0 + r0) * DM + scol;
  const u16* Bg1 = Bt + (size_t)(n0 + 128 + r0) * DM + scol;
  int d0 = t * 8, d1 = 4096 + t * 8;         // linear LDS dests (elements)

  // fragment reads: row*32 + (quad ^ ((row>>1)&3))*8 ; (row>>1)&3 == (m16>>1)&3
  int ka = (quad ^ ((m16 >> 1) & 3)) * 8;
  int aoff = (wm * 128 + m16) * 32 + ka;
  int boff = (wn * 64 + m16) * 32 + ka;

  f32x4 acc[8][4];
#pragma unroll
  for (int mi = 0; mi < 8; ++mi)
#pragma unroll
    for (int ni = 0; ni < 4; ++ni)
#pragma unroll
      for (int r = 0; r < 4; ++r) acc[mi][ni][r] = 0.f;

  // prologue: stage tiles 0..2 (12 loads/thread), wait tile 0 (2 tiles stay in flight)
#pragma unroll
  for (int kt = 0; kt < 3; ++kt) {
    GLOAD_LDS16(Ag0 + kt * 32, lA[kt] + d0);
    GLOAD_LDS16(Ag1 + kt * 32, lA[kt] + d1);
    GLOAD_LDS16(Bg0 + kt * 32, lB[kt] + d0);
    GLOAD_LDS16(Bg1 + kt * 32, lB[kt] + d1);
  }
  asm volatile("s_waitcnt vmcnt(8)" ::: "memory");
  __builtin_amdgcn_s_barrier();
  __builtin_amdgcn_sched_barrier(0);

  // initial phase-0 fragments of tile 0 (ping-pong set 0)
  s16x8 fa0[4], fb0[4], fa1[4], fb1[4];
#pragma unroll
  for (int ni = 0; ni < 4; ++ni) fb0[ni] = *(const s16x8*)&lB[0][boff + ni * 512];
#pragma unroll
  for (int mi = 0; mi < 4; ++mi) fa0[mi] = *(const s16x8*)&lA[0][aoff + mi * 512];

  // main loop: tiles 0..27 (pairs keep the reg ping-pong static)
  for (int it = 0; it < 14; ++it) {
    int T = 2 * it;
    tile_step<1, 8, 0>(lA[T & 3], lB[T & 3], lA[(T + 1) & 3], lB[(T + 1) & 3],
                       lA[(T + 3) & 3], lB[(T + 3) & 3],
                       Ag0 + (T + 3) * 32, Ag1 + (T + 3) * 32,
                       Bg0 + (T + 3) * 32, Bg1 + (T + 3) * 32,
                       d0, d1, aoff, boff, fa0, fb0, fa1, fb1, acc);
    tile_step<1, 8, 0>(lA[(T + 1) & 3], lB[(T + 1) & 3], lA[(T + 2) & 3], lB[(T + 2) & 3],
                       lA[(T + 4) & 3], lB[(T + 4) & 3],
                       Ag0 + (T + 4) * 32, Ag1 + (T + 4) * 32,
                       Bg0 + (T + 4) * 32, Bg1 + (T + 4) * 32,
                       d0, d1, aoff, boff, fa1, fb1, fa0, fb0, acc);
  }
  // tile 28 (stages tile 31), then 29,30,31 draining vmcnt 8 -> 4 -> 0
  tile_step<1, 8, 0>(lA[0], lB[0], lA[1], lB[1], lA[3], lB[3],
                     Ag0 + 31 * 32, Ag1 + 31 * 32, Bg0 + 31 * 32, Bg1 + 31 * 32,
                     d0, d1, aoff, boff, fa0, fb0, fa1, fb1, acc);
  tile_step<0, 4, 0>(lA[1], lB[1], lA[2], lB[2], lA[0], lB[0],
                     Ag0, Ag1, Bg0, Bg1, d0, d1, aoff, boff, fa1, fb1, fa0, fb0, acc);
  tile_step<0, 0, 0>(lA[2], lB[2], lA[3], lB[3], lA[0], lB[0],
                     Ag0, Ag1, Bg0, Bg1, d0, d1, aoff, boff, fa0, fb0, fa1, fb1, acc);
  tile_step<0, -1, 1>(lA[3], lB[3], lA[0], lB[0], lA[0], lB[0],
                      Ag0, Ag1, Bg0, Bg1, d0, d1, aoff, boff, fa1, fb1, fa0, fb0, acc);

  // epilogue: split Q (scaled) / K / V (transposed) — per-wave 64-col span stays
  // within one section and one head (n0, wn*64 are 64-aligned)
#pragma unroll
  for (int mi = 0; mi < 8; ++mi) {
    int gr = m0 + wm * 128 + mi * 16 + quad * 4;   // multiple of 4, no batch crossing
    int b = gr >> 11, tt = gr & 2047;
#pragma unroll
    for (int ni = 0; ni < 4; ++ni) {
      int gc = n0 + wn * 64 + ni * 16 + m16;
      int sec = gc >> 10, rem = gc & 1023, h = rem >> 6, d = rem & 63;
      if (sec == 0) {
#pragma unroll
        for (int r = 0; r < 4; ++r)
          Qo[(((size_t)b * NH + h) * SEQ + tt + r) * HD + d] = f32_bf16(acc[mi][ni][r] * QSCALE);
      } else if (sec == 1) {
#pragma unroll
        for (int r = 0; r < 4; ++r)
          Ko[(((size_t)b * NH + h) * SEQ + tt + r) * HD + d] = f32_bf16(acc[mi][ni][r]);
      } else {
        ushort4 o;
        o.x = f32_bf16(acc[mi][ni][0]); o.y = f32_bf16(acc[mi][ni][1]);
        o.z = f32_bf16(acc[mi][ni][2]); o.w = f32_bf16(acc[mi][ni][3]);
        *(ushort4*)&Vo[(((size_t)b * NH + h) * HD + d) * SEQ + tt] = o;  // V^T [b][h][d][t]
      }
    }
  }
}

// ---------------- GEMM (out-proj): C[M,N] = A[M,K] * Bt[N,K]^T, bf16 in, fp32 out ----
template<int EPI>
__global__ __launch_bounds__(256) void gemm_bt(
    const u16* __restrict__ A, const u16* __restrict__ Bt,
    float* __restrict__ Cf, u16* __restrict__ Qo, u16* __restrict__ Ko, u16* __restrict__ Vo,
    int M, int N, int K)
{
  __shared__ u16 As[128 * 32];
  __shared__ u16 Bs[128 * 32];
  int t = threadIdx.x;
  int m0 = blockIdx.y * 128, n0 = blockIdx.x * 128;

  int srow = t >> 2, scol8 = (t & 3) * 8;
  const u16* Ag0 = A  + (size_t)(m0 + srow) * K + scol8;
  const u16* Ag1 = A  + (size_t)(m0 + 64 + srow) * K + scol8;
  const u16* Bg0 = Bt + (size_t)(n0 + srow) * K + scol8;
  const u16* Bg1 = Bt + (size_t)(n0 + 64 + srow) * K + scol8;
  u16* Al0 = As + t * 8;  u16* Al1 = As + 2048 + t * 8;
  u16* Bl0 = Bs + t * 8;  u16* Bl1 = Bs + 2048 + t * 8;

  int lane = t & 63, w = t >> 6;
  int m16 = lane & 15, quad = lane >> 4;
  int wr = (w >> 1) * 64, wc = (w & 1) * 64;

  f32x4 acc[4][4];
#pragma unroll
  for (int mi = 0; mi < 4; ++mi)
#pragma unroll
    for (int ni = 0; ni < 4; ++ni)
#pragma unroll
      for (int r = 0; r < 4; ++r) acc[mi][ni][r] = 0.f;

  for (int k0 = 0; k0 < K; k0 += 32) {
    __syncthreads();
    GLOAD_LDS16(Ag0 + k0, Al0);
    GLOAD_LDS16(Ag1 + k0, Al1);
    GLOAD_LDS16(Bg0 + k0, Bl0);
    GLOAD_LDS16(Bg1 + k0, Bl1);
    __syncthreads();
    s16x8 af[4], bf[4];
#pragma unroll
    for (int mi = 0; mi < 4; ++mi)
      af[mi] = *(const s16x8*)(As + (wr + mi * 16 + m16) * 32 + quad * 8);
#pragma unroll
    for (int ni = 0; ni < 4; ++ni)
      bf[ni] = *(const s16x8*)(Bs + (wc + ni * 16 + m16) * 32 + quad * 8);
#pragma unroll
    for (int mi = 0; mi < 4; ++mi)
#pragma unroll
      for (int ni = 0; ni < 4; ++ni)
        acc[mi][ni] = __builtin_amdgcn_mfma_f32_16x16x32_bf16(af[mi], bf[ni], acc[mi][ni], 0, 0, 0);
  }

  if (EPI == 0) {
#pragma unroll
    for (int mi = 0; mi < 4; ++mi) {
      int gr = m0 + wr + mi * 16 + quad * 4;
#pragma unroll
      for (int ni = 0; ni < 4; ++ni) {
        int gc = n0 + wc + ni * 16 + m16;
#pragma unroll
        for (int r = 0; r < 4; ++r)
          Cf[(size_t)(gr + r) * N + gc] = acc[mi][ni][r];
      }
    }
  } else {
#pragma unroll
    for (int mi = 0; mi < 4; ++mi) {
      int gr = m0 + wr + mi * 16 + quad * 4;
      int b = gr >> 11, tt = gr & 2047;
#pragma unroll
      for (int ni = 0; ni < 4; ++ni) {
        int gc = n0 + wc + ni * 16 + m16;
        int sec = gc >> 10, rem = gc & 1023, h = rem >> 6, d = rem & 63;
        if (sec == 0) {
#pragma unroll
          for (int r = 0; r < 4; ++r)
            Qo[(((size_t)b * NH + h) * SEQ + tt + r) * HD + d] = f32_bf16(acc[mi][ni][r] * QSCALE);
        } else if (sec == 1) {
#pragma unroll
          for (int r = 0; r < 4; ++r)
            Ko[(((size_t)b * NH + h) * SEQ + tt + r) * HD + d] = f32_bf16(acc[mi][ni][r]);
        } else {
          ushort4 o;
          o.x = f32_bf16(acc[mi][ni][0]); o.y = f32_bf16(acc[mi][ni][1]);
          o.z = f32_bf16(acc[mi][ni][2]); o.w = f32_bf16(acc[mi][ni][3]);
          *(ushort4*)&Vo[(((size_t)b * NH + h) * HD + d) * SEQ + tt] = o;
        }
      }
    }
  }
}

// ---------------- flash attention, causal, QBLK=128, swapped-QK^T, NO-MAX softmax ------
// grid (8, 64); block 256 = 4 waves, each wave owns 32 q-rows (two 16-row frag sets).
// Block xb does q-tiles {xb, 15-xb} of 128 rows: 34 k-tile units per block, uniform.
// XCD grouping: 8 blocks of one bh land on one XCD (8 bh/XCD -> K+V in L2).
// NEW (R6): K/V double-buffered in LDS. Loads for tile kt+2 are issued right after the
// ds_write of tile kt+1, so global-load latency (~200-900 cyc) hides under the FULL
// compute of tile kt+1 instead of being exposed at every tile boundary (34x per block).
// Schedule per tile: compute(kt)[buf kt&1] -> bar -> ds_write(kt+1 -> buf (kt+1)&1)
// -> issue loads(kt+2) -> bar. WAR: all waves passed bar after compute(kt), so reads
// of buf (kt+1)&1 (last touched in compute(kt-1)) are done. RAW: writes before bar2.
__global__ __launch_bounds__(256) void attn_k(
    const u16* __restrict__ Q, const u16* __restrict__ K,
    const u16* __restrict__ Vt_g,   // [B,H,HD,SEQ]
    u16* __restrict__ O)
{
  __shared__ u16 Ks[2][64][72];   // [buf][key][d]   (144B rows: 16B-aligned)
  __shared__ u16 Vt[2][64][72];   // [buf][d][key]
  __shared__ u16 Ps[4][32][72];   // per wave: [qrow 0..31][key]
  int flat = blockIdx.y * 8 + blockIdx.x;    // grid (8, 64) = 512 blocks
  int xcd = flat & 7, pos = flat >> 3;
  int bh = xcd * 8 + (pos >> 3);             // 8 bh per XCD
  int xb = pos & 7;                          // 0..7
  int t = threadIdx.x, w = t >> 6, lane = t & 63;
  int m16 = lane & 15, quad = lane >> 4;
  int b = bh >> 4, h = bh & 15;

  int srow = t >> 2, sc = (t & 3) * 16;
  const u16* Kg0 = K    + ((size_t)bh * SEQ + srow) * HD  + sc;   // key=srow, d=sc..
  const u16* Vg0 = Vt_g + ((size_t)bh * HD  + srow) * SEQ + sc;   // d=srow,  key=sc..

  for (int half = 0; half < 2; ++half) {
    int qt = half ? (15 - xb) : xb;
    int q0 = qt * 128;

    // Q frags: set A rows q0 + w*32 + m16, set B rows +16 (scale pre-folded into Q)
    const u16* QbA = Q + ((size_t)bh * SEQ + q0 + w * 32 + m16) * HD + quad * 8;
    s16x8 qA0 = *(const s16x8*)QbA;
    s16x8 qA1 = *(const s16x8*)(QbA + 32);
    s16x8 qB0 = *(const s16x8*)(QbA + 16 * HD);
    s16x8 qB1 = *(const s16x8*)(QbA + 16 * HD + 32);

    f32x4 accA[4], accB[4];
    float lA = 0.f, lB = 0.f;
#pragma unroll
    for (int ni = 0; ni < 4; ++ni)
#pragma unroll
      for (int r = 0; r < 4; ++r) { accA[ni][r] = 0.f; accB[ni][r] = 0.f; }

    int ktmax = 2 * qt + 1;   // >= 1 always

    // prologue: tile 0 -> buf 0; issue tile-1 loads (hide under first compute)
    uint4 kv0 = *(const uint4*)(Kg0);
    uint4 kv1 = *(const uint4*)(Kg0 + 8);
    uint4 vv0 = *(const uint4*)(Vg0);
    uint4 vv1 = *(const uint4*)(Vg0 + 8);
    __syncthreads();   // WAR vs previous half's LDS reads
    *(uint4*)&Ks[0][srow][sc]     = kv0;
    *(uint4*)&Ks[0][srow][sc + 8] = kv1;
    *(uint4*)&Vt[0][srow][sc]     = vv0;
    *(uint4*)&Vt[0][srow][sc + 8] = vv1;
    kv0 = *(const uint4*)(Kg0 + (size_t)64 * HD);
    kv1 = *(const uint4*)(Kg0 + (size_t)64 * HD + 8);
    vv0 = *(const uint4*)(Vg0 + 64);
    vv1 = *(const uint4*)(Vg0 + 64 + 8);
    __syncthreads();

    for (int kt = 0; kt <= ktmax; ++kt) {
      int cur = kt & 1;

      // S^T = K Q^T
      f32x4 sA[4], sB[4];
#pragma unroll
      for (int ni = 0; ni < 4; ++ni)
#pragma unroll
        for (int r = 0; r < 4; ++r) { sA[ni][r] = 0.f; sB[ni][r] = 0.f; }
#pragma unroll
      for (int ni = 0; ni < 4; ++ni) {
        s16x8 kf0 = *(const s16x8*)&Ks[cur][ni * 16 + m16][quad * 8];
        s16x8 kf1 = *(const s16x8*)&Ks[cur][ni * 16 + m16][32 + quad * 8];
        sA[ni] = mfma16(kf0, qA0, sA[ni]);
        sA[ni] = mfma16(kf1, qA1, sA[ni]);
        sB[ni] = mfma16(kf0, qB0, sB[ni]);
        sB[ni] = mfma16(kf1, qB1, sB[ni]);
      }
      if (kt >= 2 * qt) {   // diagonal region: causal mask (exp2(-1e30) -> 0)
        int qga = q0 + w * 32 + m16;
#pragma unroll
        for (int ni = 0; ni < 4; ++ni) {
          int kb = kt * 64 + ni * 16 + quad * 4;
#pragma unroll
          for (int r = 0; r < 4; ++r) {
            if (kb + r > qga)      sA[ni][r] = -1e30f;
            if (kb + r > qga + 16) sB[ni][r] = -1e30f;
          }
        }
      }

      // p = exp2(S); per-lane l partial (q = m16 row); P write as ushort4 (b64)
#pragma unroll
      for (int ni = 0; ni < 4; ++ni) {
        ushort4 oA, oB;
#pragma unroll
        for (int r = 0; r < 4; ++r) {
          float pA = __builtin_amdgcn_exp2f(sA[ni][r]);
          float pB = __builtin_amdgcn_exp2f(sB[ni][r]);
          lA += pA; lB += pB;
          ((u16*)&oA)[r] = f32_bf16_trunc(pA);
          ((u16*)&oB)[r] = f32_bf16_trunc(pB);
        }
        *(ushort4*)&Ps[w][m16][ni * 16 + quad * 4]      = oA;
        *(ushort4*)&Ps[w][16 + m16][ni * 16 + quad * 4] = oB;
      }

      // no barrier: Ps is same-wave write->read, ordered by lgkmcnt
#pragma unroll
      for (int ks = 0; ks < 2; ++ks) {
        s16x8 pA = *(const s16x8*)&Ps[w][m16][ks * 32 + quad * 8];
        s16x8 pB = *(const s16x8*)&Ps[w][16 + m16][ks * 32 + quad * 8];
#pragma unroll
        for (int ni = 0; ni < 4; ++ni) {
          s16x8 vf = *(const s16x8*)&Vt[cur][ni * 16 + m16][ks * 32 + quad * 8];
          accA[ni] = mfma16(pA, vf, accA[ni]);
          accB[ni] = mfma16(pB, vf, accB[ni]);
        }
      }

      // stage next tile into the other buffer; issue kt+2 loads (hide under next compute)
      if (kt < ktmax) {
        int nxt = (kt + 1) & 1;
        __syncthreads();   // all waves done reading buf nxt (compute kt-1)
        *(uint4*)&Ks[nxt][srow][sc]     = kv0;
        *(uint4*)&Ks[nxt][srow][sc + 8] = kv1;
        *(uint4*)&Vt[nxt][srow][sc]     = vv0;
        *(uint4*)&Vt[nxt][srow][sc + 8] = vv1;
        if (kt + 2 <= ktmax) {
          kv0 = *(const uint4*)(Kg0 + (size_t)(kt + 2) * 64 * HD);
          kv1 = *(const uint4*)(Kg0 + (size_t)(kt + 2) * 64 * HD + 8);
          vv0 = *(const uint4*)(Vg0 + (kt + 2) * 64);
          vv1 = *(const uint4*)(Vg0 + (kt + 2) * 64 + 8);
        }
        __syncthreads();
      }
    }

    // l: reduce over the 4 quad lanes (keys split across quads)
    lA += __shfl_xor(lA, 16, 64);
    lA += __shfl_xor(lA, 32, 64);
    lB += __shfl_xor(lB, 16, 64);
    lB += __shfl_xor(lB, 32, 64);

    // epilogue: O rows q = q0 + w*32 + (quad*4+r) [+16 for set B]; l lives at
    // lanes with m16 == qrow -> redistribute with one shfl per r
#pragma unroll
    for (int r = 0; r < 4; ++r) {
      int src = (lane & 48) | (quad * 4 + r);
      float la = __shfl(lA, src, 64);
      float lb = __shfl(lB, src, 64);
      float ia = 1.f / la, ib = 1.f / lb;
      int qa = q0 + w * 32 + quad * 4 + r;
      size_t baseA = ((size_t)(b * SEQ + qa)) * DM + h * HD;
      size_t baseB = baseA + (size_t)16 * DM;
#pragma unroll
      for (int ni = 0; ni < 4; ++ni) {
        O[baseA + ni * 16 + m16] = f32_bf16(accA[ni][r] * ia);
        O[baseB + ni * 16 + m16] = f32_bf16(accB[ni][r] * ib);
      }
    }
  }
}

// ---------------- launch ----------------
extern "C" void kernel_launch(void* const* d_in, const int* in_sizes, int n_in,
                              void* d_out, int out_size, void* d_ws, size_t ws_size,
                              hipStream_t stream) {
  const float* x    = (const float*)d_in[0];   // [4,2048,1024]
  const float* Wqkv = (const float*)d_in[1];   // [1024,3072]
  const float* Wout = (const float*)d_in[2];   // [1024,1024]
  float* out = (float*)d_out;                  // [4,2048,1024] fp32

  u16* ws = (u16*)d_ws;
  size_t off = 0;
  u16* x_bf   = ws + off; off += (size_t)ROWS * DM;
  u16* wqkv_t = ws + off; off += (size_t)(3 * DM) * DM;
  u16* wout_t = ws + off; off += (size_t)DM * DM;
  u16* Qb     = ws + off; off += (size_t)BATCH * NH * SEQ * HD;
  u16* Kb     = ws + off; off += (size_t)BATCH * NH * SEQ * HD;
  u16* Vb     = ws + off; off += (size_t)BATCH * NH * SEQ * HD;  // [B,H,HD,T]
  u16* AO     = ws + off; off += (size_t)ROWS * DM;

  cast_bf16_k<<<(ROWS * DM / 4 + 255) / 256, 256, 0, stream>>>(x, x_bf, ROWS * DM / 4);
  cast_transpose_k<<<dim3(3 * DM / 32, DM / 32), 256, 0, stream>>>(Wqkv, wqkv_t, DM, 3 * DM);
  cast_transpose_k<<<dim3(DM / 32, DM / 32), 256, 0, stream>>>(Wout, wout_t, DM, DM);
  qkv_gemm<<<dim3(12, 32), 512, 0, stream>>>(x_bf, wqkv_t, Qb, Kb, Vb);
  attn_k<<<dim3(8, BATCH * NH), 256, 0, stream>>>(Qb, Kb, Vb, AO);
  gemm_bt<0><<<dim3(DM / 128, ROWS / 128), 256, 0, stream>>>(
      AO, wout_t, out, nullptr, nullptr, nullptr, ROWS, DM, DM);
}

// Round 7
// 255.749 us; speedup vs baseline: 1.5403x; 1.1103x over previous
//
#include <hip/hip_runtime.h>
#include <stdint.h>

typedef unsigned short u16;
typedef float f32x4 __attribute__((ext_vector_type(4)));
typedef short s16x8 __attribute__((ext_vector_type(8)));

#define SEQ 2048
#define DM 1024
#define NH 16
#define HD 64
#define BATCH 4
#define ROWS (BATCH*SEQ)   // 8192

__device__ __forceinline__ u16 f32_bf16(float f) {
  union { float f; uint32_t u; } c; c.f = f;
  uint32_t u = c.u;
  return (u16)((u + 0x7fffu + ((u >> 16) & 1u)) >> 16);  // RNE
}
// truncating cast (for P >= 0: bias cancels in softmax normalization)
__device__ __forceinline__ u16 f32_bf16_trunc(float f) {
  union { float f; uint32_t u; } c; c.f = f;
  return (u16)(c.u >> 16);
}

// async global->LDS, 16B per lane. LDS dest = wave-uniform base + lane*16 (NO padding).
#define GLOAD_LDS16(g, l) __builtin_amdgcn_global_load_lds( \
    (__attribute__((address_space(1))) void*)(g),           \
    (__attribute__((address_space(3))) void*)(l), 16, 0, 0)

// ---------------- cast kernels ----------------
__global__ __launch_bounds__(256) void cast_bf16_k(const float* __restrict__ in,
                                                   u16* __restrict__ out, int n4) {
  int i = blockIdx.x * 256 + threadIdx.x;
  if (i >= n4) return;
  float4 v = ((const float4*)in)[i];
  ushort4 o;
  o.x = f32_bf16(v.x); o.y = f32_bf16(v.y); o.z = f32_bf16(v.z); o.w = f32_bf16(v.w);
  ((ushort4*)out)[i] = o;
}

// in [R][C] fp32  ->  out [C][R] bf16
__global__ __launch_bounds__(256) void cast_transpose_k(const float* __restrict__ in,
                                                        u16* __restrict__ out, int R, int C) {
  __shared__ float tile[32][33];
  int c0 = blockIdx.x * 32, r0 = blockIdx.y * 32;
  int t = threadIdx.x;
  int lr = t >> 3, lc = (t & 7) * 4;
  float4 v = *(const float4*)(in + (size_t)(r0 + lr) * C + c0 + lc);
  tile[lr][lc] = v.x; tile[lr][lc + 1] = v.y; tile[lr][lc + 2] = v.z; tile[lr][lc + 3] = v.w;
  __syncthreads();
  ushort4 o;
  o.x = f32_bf16(tile[lc + 0][lr]);
  o.y = f32_bf16(tile[lc + 1][lr]);
  o.z = f32_bf16(tile[lc + 2][lr]);
  o.w = f32_bf16(tile[lc + 3][lr]);
  *(ushort4*)(out + (size_t)(c0 + lr) * R + r0 + lc) = o;
}

#define QSCALE 0.18033688011112042f   // (1/sqrt(64)) * log2(e)

// ---------------- QKV GEMM: 256x256 tile, BK=32, ring-4 LDS, overlapped pipeline ------
// (R4 schedule, verbatim: 82.4 us measured, 0 bank conflicts, no spill.
//  acc[8][4]=128 + ping-pong frags 80 + f1 16 ~= 230 VGPR < 256 cap. Do NOT widen the
//  tile: 256x384 needs ~320 VGPR -> spills to scratch (654 MB WRITE_SIZE, R5).
//  R7: XCD patch reshaped 4x12 -> 8x6 (per-XCD L2 working set 8 MB -> 7 MB).)

__device__ __forceinline__ f32x4 mfma16(s16x8 a, s16x8 b, f32x4 c) {
  return __builtin_amdgcn_mfma_f32_16x16x32_bf16(a, b, c, 0, 0, 0);
}

template<int STG, int ENDVM, int LAST>
__device__ __forceinline__ void tile_step(
    const u16* lAc, const u16* lBc,   // buf T (current)
    const u16* lAn, const u16* lBn,   // buf T+1 (next; frag prefetch source)
    u16* lAs, u16* lBs,               // buf T+3 (stage dest)
    const u16* gA0, const u16* gA1, const u16* gB0, const u16* gB1,
    int d0, int d1, int aoff, int boff,
    s16x8 (&fa)[4], s16x8 (&fb)[4],   // tile T phase-0 frags (preloaded last tile)
    s16x8 (&na)[4], s16x8 (&nb)[4],   // tile T+1 frag storage (ping-pong)
    f32x4 (&acc)[8][4])
{
  __builtin_amdgcn_s_barrier();                       // bar2 (WAR fence for stage)
  __builtin_amdgcn_sched_barrier(0);
  s16x8 f1[4];                                        // A-high frags of tile T
#pragma unroll
  for (int mi = 0; mi < 4; ++mi) f1[mi] = *(const s16x8*)&lAc[aoff + 2048 + mi * 512];
  if (STG) { GLOAD_LDS16(gA0, lAs + d0); GLOAD_LDS16(gA1, lAs + d1); }
  asm volatile("s_waitcnt lgkmcnt(4)" ::: "memory");  // fa/fb resident; f1 in flight
  __builtin_amdgcn_sched_barrier(0);
  __builtin_amdgcn_s_setprio(1);
#pragma unroll
  for (int mi = 0; mi < 4; ++mi)
#pragma unroll
    for (int ni = 0; ni < 4; ++ni)
      acc[mi][ni] = mfma16(fa[mi], fb[ni], acc[mi][ni]);
  __builtin_amdgcn_s_setprio(0);
  __builtin_amdgcn_sched_barrier(0);
  if (STG) { GLOAD_LDS16(gB0, lBs + d0); GLOAD_LDS16(gB1, lBs + d1); }
  if (ENDVM == 8)      asm volatile("s_waitcnt vmcnt(8)" ::: "memory");
  else if (ENDVM == 4) asm volatile("s_waitcnt vmcnt(4)" ::: "memory");
  else if (ENDVM == 0) asm volatile("s_waitcnt vmcnt(0)" ::: "memory");
  __builtin_amdgcn_s_barrier();                       // bar1: buf T+1 ready for reads
  __builtin_amdgcn_sched_barrier(0);
  if (!LAST) {
#pragma unroll
    for (int ni = 0; ni < 4; ++ni) nb[ni] = *(const s16x8*)&lBn[boff + ni * 512];
#pragma unroll
    for (int mi = 0; mi < 4; ++mi) na[mi] = *(const s16x8*)&lAn[aoff + mi * 512];
    asm volatile("s_waitcnt lgkmcnt(8)" ::: "memory"); // f1 resident; na/nb in flight
  } else {
    asm volatile("s_waitcnt lgkmcnt(0)" ::: "memory");
  }
  __builtin_amdgcn_sched_barrier(0);
  __builtin_amdgcn_s_setprio(1);
#pragma unroll
  for (int mi = 0; mi < 4; ++mi)
#pragma unroll
    for (int ni = 0; ni < 4; ++ni)
      acc[4 + mi][ni] = mfma16(f1[mi], fb[ni], acc[4 + mi][ni]);
  __builtin_amdgcn_s_setprio(0);
  __builtin_amdgcn_sched_barrier(0);
}

__global__ __launch_bounds__(512, 2) void qkv_gemm(
    const u16* __restrict__ A, const u16* __restrict__ Bt,
    u16* __restrict__ Qo, u16* __restrict__ Ko, u16* __restrict__ Vo)
{
  __shared__ u16 lA[4][8192];   // 4 ring bufs x [256 rows][32 k] bf16
  __shared__ u16 lB[4][8192];
  int t = threadIdx.x;

  // XCD-aware bijective remap: 8 XCDs as 4(m) x 2(n); each XCD owns an 8x6 block patch
  // (A 4 MB + B 3 MB = 7 MB working set; was 4x12 -> 8 MB)
  int flat = blockIdx.y * 12 + blockIdx.x;   // grid (12, 32), 384 blocks
  int xcd = flat & 7, idx = flat >> 3;       // idx 0..47
  int by = (xcd >> 1) * 8 + idx / 6;
  int bx = (xcd & 1) * 6 + idx % 6;
  int m0 = by * 256, n0 = bx * 256;

  int lane = t & 63, w = t >> 6;
  int m16 = lane & 15, quad = lane >> 4;
  int wm = w >> 2, wn = w & 3;               // 2 x 4 wave grid

  // staging: 1024 16B-chunks per 16KB operand tile; thread t covers chunks t, 512+t.
  // chunk c: row = c>>2, in-row slot j = c&3; source slot = j ^ ((c>>3)&3) (involution).
  int r0 = t >> 2;
  int scol = ((t & 3) ^ ((t >> 3) & 3)) * 8; // pre-swizzled source column (elements)
  const u16* Ag0 = A  + (size_t)(m0 + r0) * DM + scol;
  const u16* Ag1 = A  + (size_t)(m0 + 128 + r0) * DM + scol;
  const u16* Bg0 = Bt + (size_t)(n0 + r0) * DM + scol;
  const u16* Bg1 = Bt + (size_t)(n0 + 128 + r0) * DM + scol;
  int d0 = t * 8, d1 = 4096 + t * 8;         // linear LDS dests (elements)

  // fragment reads: row*32 + (quad ^ ((row>>1)&3))*8 ; (row>>1)&3 == (m16>>1)&3
  int ka = (quad ^ ((m16 >> 1) & 3)) * 8;
  int aoff = (wm * 128 + m16) * 32 + ka;
  int boff = (wn * 64 + m16) * 32 + ka;

  f32x4 acc[8][4];
#pragma unroll
  for (int mi = 0; mi < 8; ++mi)
#pragma unroll
    for (int ni = 0; ni < 4; ++ni)
#pragma unroll
      for (int r = 0; r < 4; ++r) acc[mi][ni][r] = 0.f;

  // prologue: stage tiles 0..2 (12 loads/thread), wait tile 0 (2 tiles stay in flight)
#pragma unroll
  for (int kt = 0; kt < 3; ++kt) {
    GLOAD_LDS16(Ag0 + kt * 32, lA[kt] + d0);
    GLOAD_LDS16(Ag1 + kt * 32, lA[kt] + d1);
    GLOAD_LDS16(Bg0 + kt * 32, lB[kt] + d0);
    GLOAD_LDS16(Bg1 + kt * 32, lB[kt] + d1);
  }
  asm volatile("s_waitcnt vmcnt(8)" ::: "memory");
  __builtin_amdgcn_s_barrier();
  __builtin_amdgcn_sched_barrier(0);

  // initial phase-0 fragments of tile 0 (ping-pong set 0)
  s16x8 fa0[4], fb0[4], fa1[4], fb1[4];
#pragma unroll
  for (int ni = 0; ni < 4; ++ni) fb0[ni] = *(const s16x8*)&lB[0][boff + ni * 512];
#pragma unroll
  for (int mi = 0; mi < 4; ++mi) fa0[mi] = *(const s16x8*)&lA[0][aoff + mi * 512];

  // main loop: tiles 0..27 (pairs keep the reg ping-pong static)
  for (int it = 0; it < 14; ++it) {
    int T = 2 * it;
    tile_step<1, 8, 0>(lA[T & 3], lB[T & 3], lA[(T + 1) & 3], lB[(T + 1) & 3],
                       lA[(T + 3) & 3], lB[(T + 3) & 3],
                       Ag0 + (T + 3) * 32, Ag1 + (T + 3) * 32,
                       Bg0 + (T + 3) * 32, Bg1 + (T + 3) * 32,
                       d0, d1, aoff, boff, fa0, fb0, fa1, fb1, acc);
    tile_step<1, 8, 0>(lA[(T + 1) & 3], lB[(T + 1) & 3], lA[(T + 2) & 3], lB[(T + 2) & 3],
                       lA[(T + 4) & 3], lB[(T + 4) & 3],
                       Ag0 + (T + 4) * 32, Ag1 + (T + 4) * 32,
                       Bg0 + (T + 4) * 32, Bg1 + (T + 4) * 32,
                       d0, d1, aoff, boff, fa1, fb1, fa0, fb0, acc);
  }
  // tile 28 (stages tile 31), then 29,30,31 draining vmcnt 8 -> 4 -> 0
  tile_step<1, 8, 0>(lA[0], lB[0], lA[1], lB[1], lA[3], lB[3],
                     Ag0 + 31 * 32, Ag1 + 31 * 32, Bg0 + 31 * 32, Bg1 + 31 * 32,
                     d0, d1, aoff, boff, fa0, fb0, fa1, fb1, acc);
  tile_step<0, 4, 0>(lA[1], lB[1], lA[2], lB[2], lA[0], lB[0],
                     Ag0, Ag1, Bg0, Bg1, d0, d1, aoff, boff, fa1, fb1, fa0, fb0, acc);
  tile_step<0, 0, 0>(lA[2], lB[2], lA[3], lB[3], lA[0], lB[0],
                     Ag0, Ag1, Bg0, Bg1, d0, d1, aoff, boff, fa0, fb0, fa1, fb1, acc);
  tile_step<0, -1, 1>(lA[3], lB[3], lA[0], lB[0], lA[0], lB[0],
                      Ag0, Ag1, Bg0, Bg1, d0, d1, aoff, boff, fa1, fb1, fa0, fb0, acc);

  // epilogue: split Q (scaled) / K / V (transposed) — per-wave 64-col span stays
  // within one section and one head (n0, wn*64 are 64-aligned)
#pragma unroll
  for (int mi = 0; mi < 8; ++mi) {
    int gr = m0 + wm * 128 + mi * 16 + quad * 4;   // multiple of 4, no batch crossing
    int b = gr >> 11, tt = gr & 2047;
#pragma unroll
    for (int ni = 0; ni < 4; ++ni) {
      int gc = n0 + wn * 64 + ni * 16 + m16;
      int sec = gc >> 10, rem = gc & 1023, h = rem >> 6, d = rem & 63;
      if (sec == 0) {
#pragma unroll
        for (int r = 0; r < 4; ++r)
          Qo[(((size_t)b * NH + h) * SEQ + tt + r) * HD + d] = f32_bf16(acc[mi][ni][r] * QSCALE);
      } else if (sec == 1) {
#pragma unroll
        for (int r = 0; r < 4; ++r)
          Ko[(((size_t)b * NH + h) * SEQ + tt + r) * HD + d] = f32_bf16(acc[mi][ni][r]);
      } else {
        ushort4 o;
        o.x = f32_bf16(acc[mi][ni][0]); o.y = f32_bf16(acc[mi][ni][1]);
        o.z = f32_bf16(acc[mi][ni][2]); o.w = f32_bf16(acc[mi][ni][3]);
        *(ushort4*)&Vo[(((size_t)b * NH + h) * HD + d) * SEQ + tt] = o;  // V^T [b][h][d][t]
      }
    }
  }
}

// ---------------- GEMM (out-proj): C[M,N] = A[M,K] * Bt[N,K]^T, bf16 in, fp32 out ----
template<int EPI>
__global__ __launch_bounds__(256) void gemm_bt(
    const u16* __restrict__ A, const u16* __restrict__ Bt,
    float* __restrict__ Cf, u16* __restrict__ Qo, u16* __restrict__ Ko, u16* __restrict__ Vo,
    int M, int N, int K)
{
  __shared__ u16 As[128 * 32];
  __shared__ u16 Bs[128 * 32];
  int t = threadIdx.x;
  int m0 = blockIdx.y * 128, n0 = blockIdx.x * 128;

  int srow = t >> 2, scol8 = (t & 3) * 8;
  const u16* Ag0 = A  + (size_t)(m0 + srow) * K + scol8;
  const u16* Ag1 = A  + (size_t)(m0 + 64 + srow) * K + scol8;
  const u16* Bg0 = Bt + (size_t)(n0 + srow) * K + scol8;
  const u16* Bg1 = Bt + (size_t)(n0 + 64 + srow) * K + scol8;
  u16* Al0 = As + t * 8;  u16* Al1 = As + 2048 + t * 8;
  u16* Bl0 = Bs + t * 8;  u16* Bl1 = Bs + 2048 + t * 8;

  int lane = t & 63, w = t >> 6;
  int m16 = lane & 15, quad = lane >> 4;
  int wr = (w >> 1) * 64, wc = (w & 1) * 64;

  f32x4 acc[4][4];
#pragma unroll
  for (int mi = 0; mi < 4; ++mi)
#pragma unroll
    for (int ni = 0; ni < 4; ++ni)
#pragma unroll
      for (int r = 0; r < 4; ++r) acc[mi][ni][r] = 0.f;

  for (int k0 = 0; k0 < K; k0 += 32) {
    __syncthreads();
    GLOAD_LDS16(Ag0 + k0, Al0);
    GLOAD_LDS16(Ag1 + k0, Al1);
    GLOAD_LDS16(Bg0 + k0, Bl0);
    GLOAD_LDS16(Bg1 + k0, Bl1);
    __syncthreads();
    s16x8 af[4], bf[4];
#pragma unroll
    for (int mi = 0; mi < 4; ++mi)
      af[mi] = *(const s16x8*)(As + (wr + mi * 16 + m16) * 32 + quad * 8);
#pragma unroll
    for (int ni = 0; ni < 4; ++ni)
      bf[ni] = *(const s16x8*)(Bs + (wc + ni * 16 + m16) * 32 + quad * 8);
#pragma unroll
    for (int mi = 0; mi < 4; ++mi)
#pragma unroll
      for (int ni = 0; ni < 4; ++ni)
        acc[mi][ni] = __builtin_amdgcn_mfma_f32_16x16x32_bf16(af[mi], bf[ni], acc[mi][ni], 0, 0, 0);
  }

  if (EPI == 0) {
#pragma unroll
    for (int mi = 0; mi < 4; ++mi) {
      int gr = m0 + wr + mi * 16 + quad * 4;
#pragma unroll
      for (int ni = 0; ni < 4; ++ni) {
        int gc = n0 + wc + ni * 16 + m16;
#pragma unroll
        for (int r = 0; r < 4; ++r)
          Cf[(size_t)(gr + r) * N + gc] = acc[mi][ni][r];
      }
    }
  } else {
#pragma unroll
    for (int mi = 0; mi < 4; ++mi) {
      int gr = m0 + wr + mi * 16 + quad * 4;
      int b = gr >> 11, tt = gr & 2047;
#pragma unroll
      for (int ni = 0; ni < 4; ++ni) {
        int gc = n0 + wc + ni * 16 + m16;
        int sec = gc >> 10, rem = gc & 1023, h = rem >> 6, d = rem & 63;
        if (sec == 0) {
#pragma unroll
          for (int r = 0; r < 4; ++r)
            Qo[(((size_t)b * NH + h) * SEQ + tt + r) * HD + d] = f32_bf16(acc[mi][ni][r] * QSCALE);
        } else if (sec == 1) {
#pragma unroll
          for (int r = 0; r < 4; ++r)
            Ko[(((size_t)b * NH + h) * SEQ + tt + r) * HD + d] = f32_bf16(acc[mi][ni][r]);
        } else {
          ushort4 o;
          o.x = f32_bf16(acc[mi][ni][0]); o.y = f32_bf16(acc[mi][ni][1]);
          o.z = f32_bf16(acc[mi][ni][2]); o.w = f32_bf16(acc[mi][ni][3]);
          *(ushort4*)&Vo[(((size_t)b * NH + h) * HD + d) * SEQ + tt] = o;
        }
      }
    }
  }
}

// ---------------- flash attention, causal, QBLK=128, swapped-QK^T, NO-MAX softmax ------
// (R4 version, verbatim. Single-buffer K/V = 27 KB LDS -> 4-5 blocks/CU; load latency
// hidden by inter-block TLP. R6's LDS double-buffer (54 KB -> 2 blocks/CU) REGRESSED
// 82 -> 95 us: do not trade occupancy for intra-block pipelining here.)
// grid (8, 64); block 256 = 4 waves, each wave owns 32 q-rows (two 16-row frag sets).
// Block xb does q-tiles {xb, 15-xb} of 128 rows: 34 k-tile units per block, uniform.
// XCD grouping: 8 blocks of one bh land on one XCD (8 bh/XCD -> K+V in L2).
__global__ __launch_bounds__(256) void attn_k(
    const u16* __restrict__ Q, const u16* __restrict__ K,
    const u16* __restrict__ Vt_g,   // [B,H,HD,SEQ]
    u16* __restrict__ O)
{
  __shared__ u16 Ks[64][72];      // [key][d]   (144B rows: 16B-aligned)
  __shared__ u16 Vt[64][72];      // [d][key]
  __shared__ u16 Ps[4][32][72];   // per wave: [qrow 0..31][key]
  int flat = blockIdx.y * 8 + blockIdx.x;    // grid (8, 64) = 512 blocks
  int xcd = flat & 7, pos = flat >> 3;
  int bh = xcd * 8 + (pos >> 3);             // 8 bh per XCD
  int xb = pos & 7;                          // 0..7
  int t = threadIdx.x, w = t >> 6, lane = t & 63;
  int m16 = lane & 15, quad = lane >> 4;
  int b = bh >> 4, h = bh & 15;

  int srow = t >> 2, sc = (t & 3) * 16;
  const u16* Kg0 = K    + ((size_t)bh * SEQ + srow) * HD  + sc;   // key=srow, d=sc..
  const u16* Vg0 = Vt_g + ((size_t)bh * HD  + srow) * SEQ + sc;   // d=srow,  key=sc..

  for (int half = 0; half < 2; ++half) {
    int qt = half ? (15 - xb) : xb;
    int q0 = qt * 128;

    // Q frags: set A rows q0 + w*32 + m16, set B rows +16 (scale pre-folded into Q)
    const u16* QbA = Q + ((size_t)bh * SEQ + q0 + w * 32 + m16) * HD + quad * 8;
    s16x8 qA0 = *(const s16x8*)QbA;
    s16x8 qA1 = *(const s16x8*)(QbA + 32);
    s16x8 qB0 = *(const s16x8*)(QbA + 16 * HD);
    s16x8 qB1 = *(const s16x8*)(QbA + 16 * HD + 32);

    f32x4 accA[4], accB[4];
    float lA = 0.f, lB = 0.f;
#pragma unroll
    for (int ni = 0; ni < 4; ++ni)
#pragma unroll
      for (int r = 0; r < 4; ++r) { accA[ni][r] = 0.f; accB[ni][r] = 0.f; }

    int ktmax = 2 * qt + 1;
    for (int kt = 0; kt <= ktmax; ++kt) {
      uint4 kv0 = *(const uint4*)(Kg0 + (size_t)kt * 64 * HD);
      uint4 kv1 = *(const uint4*)(Kg0 + (size_t)kt * 64 * HD + 8);
      uint4 vv0 = *(const uint4*)(Vg0 + kt * 64);
      uint4 vv1 = *(const uint4*)(Vg0 + kt * 64 + 8);
      __syncthreads();   // previous tile's LDS reads done
      *(uint4*)&Ks[srow][sc]     = kv0;
      *(uint4*)&Ks[srow][sc + 8] = kv1;
      *(uint4*)&Vt[srow][sc]     = vv0;
      *(uint4*)&Vt[srow][sc + 8] = vv1;
      __syncthreads();

      // S^T = K Q^T
      f32x4 sA[4], sB[4];
#pragma unroll
      for (int ni = 0; ni < 4; ++ni)
#pragma unroll
        for (int r = 0; r < 4; ++r) { sA[ni][r] = 0.f; sB[ni][r] = 0.f; }
#pragma unroll
      for (int ni = 0; ni < 4; ++ni) {
        s16x8 kf0 = *(const s16x8*)&Ks[ni * 16 + m16][quad * 8];
        s16x8 kf1 = *(const s16x8*)&Ks[ni * 16 + m16][32 + quad * 8];
        sA[ni] = mfma16(kf0, qA0, sA[ni]);
        sA[ni] = mfma16(kf1, qA1, sA[ni]);
        sB[ni] = mfma16(kf0, qB0, sB[ni]);
        sB[ni] = mfma16(kf1, qB1, sB[ni]);
      }
      if (kt >= 2 * qt) {   // diagonal region: causal mask (exp2(-1e30) -> 0)
        int qga = q0 + w * 32 + m16;
#pragma unroll
        for (int ni = 0; ni < 4; ++ni) {
          int kb = kt * 64 + ni * 16 + quad * 4;
#pragma unroll
          for (int r = 0; r < 4; ++r) {
            if (kb + r > qga)      sA[ni][r] = -1e30f;
            if (kb + r > qga + 16) sB[ni][r] = -1e30f;
          }
        }
      }

      // p = exp2(S); per-lane l partial (q = m16 row); P write as ushort4 (b64)
#pragma unroll
      for (int ni = 0; ni < 4; ++ni) {
        ushort4 oA, oB;
#pragma unroll
        for (int r = 0; r < 4; ++r) {
          float pA = __builtin_amdgcn_exp2f(sA[ni][r]);
          float pB = __builtin_amdgcn_exp2f(sB[ni][r]);
          lA += pA; lB += pB;
          ((u16*)&oA)[r] = f32_bf16_trunc(pA);
          ((u16*)&oB)[r] = f32_bf16_trunc(pB);
        }
        *(ushort4*)&Ps[w][m16][ni * 16 + quad * 4]      = oA;
        *(ushort4*)&Ps[w][16 + m16][ni * 16 + quad * 4] = oB;
      }

      // no barrier: Ps is same-wave write->read, ordered by lgkmcnt
#pragma unroll
      for (int ks = 0; ks < 2; ++ks) {
        s16x8 pA = *(const s16x8*)&Ps[w][m16][ks * 32 + quad * 8];
        s16x8 pB = *(const s16x8*)&Ps[w][16 + m16][ks * 32 + quad * 8];
#pragma unroll
        for (int ni = 0; ni < 4; ++ni) {
          s16x8 vf = *(const s16x8*)&Vt[ni * 16 + m16][ks * 32 + quad * 8];
          accA[ni] = mfma16(pA, vf, accA[ni]);
          accB[ni] = mfma16(pB, vf, accB[ni]);
        }
      }
    }

    // l: reduce over the 4 quad lanes (keys split across quads)
    lA += __shfl_xor(lA, 16, 64);
    lA += __shfl_xor(lA, 32, 64);
    lB += __shfl_xor(lB, 16, 64);
    lB += __shfl_xor(lB, 32, 64);

    // epilogue: O rows q = q0 + w*32 + (quad*4+r) [+16 for set B]; l lives at
    // lanes with m16 == qrow -> redistribute with one shfl per r
#pragma unroll
    for (int r = 0; r < 4; ++r) {
      int src = (lane & 48) | (quad * 4 + r);
      float la = __shfl(lA, src, 64);
      float lb = __shfl(lB, src, 64);
      float ia = 1.f / la, ib = 1.f / lb;
      int qa = q0 + w * 32 + quad * 4 + r;
      size_t baseA = ((size_t)(b * SEQ + qa)) * DM + h * HD;
      size_t baseB = baseA + (size_t)16 * DM;
#pragma unroll
      for (int ni = 0; ni < 4; ++ni) {
        O[baseA + ni * 16 + m16] = f32_bf16(accA[ni][r] * ia);
        O[baseB + ni * 16 + m16] = f32_bf16(accB[ni][r] * ib);
      }
    }
  }
}

// ---------------- launch ----------------
extern "C" void kernel_launch(void* const* d_in, const int* in_sizes, int n_in,
                              void* d_out, int out_size, void* d_ws, size_t ws_size,
                              hipStream_t stream) {
  const float* x    = (const float*)d_in[0];   // [4,2048,1024]
  const float* Wqkv = (const float*)d_in[1];   // [1024,3072]
  const float* Wout = (const float*)d_in[2];   // [1024,1024]
  float* out = (float*)d_out;                  // [4,2048,1024] fp32

  u16* ws = (u16*)d_ws;
  size_t off = 0;
  u16* x_bf   = ws + off; off += (size_t)ROWS * DM;
  u16* wqkv_t = ws + off; off += (size_t)(3 * DM) * DM;
  u16* wout_t = ws + off; off += (size_t)DM * DM;
  u16* Qb     = ws + off; off += (size_t)BATCH * NH * SEQ * HD;
  u16* Kb     = ws + off; off += (size_t)BATCH * NH * SEQ * HD;
  u16* Vb     = ws + off; off += (size_t)BATCH * NH * SEQ * HD;  // [B,H,HD,T]
  u16* AO     = ws + off; off += (size_t)ROWS * DM;

  cast_bf16_k<<<(ROWS * DM / 4 + 255) / 256, 256, 0, stream>>>(x, x_bf, ROWS * DM / 4);
  cast_transpose_k<<<dim3(3 * DM / 32, DM / 32), 256, 0, stream>>>(Wqkv, wqkv_t, DM, 3 * DM);
  cast_transpose_k<<<dim3(DM / 32, DM / 32), 256, 0, stream>>>(Wout, wout_t, DM, DM);
  qkv_gemm<<<dim3(12, 32), 512, 0, stream>>>(x_bf, wqkv_t, Qb, Kb, Vb);
  attn_k<<<dim3(8, BATCH * NH), 256, 0, stream>>>(Qb, Kb, Vb, AO);
  gemm_bt<0><<<dim3(DM / 128, ROWS / 128), 256, 0, stream>>>(
      AO, wout_t, out, nullptr, nullptr, nullptr, ROWS, DM, DM);
}